// Round 7
// baseline (209.336 us; speedup 1.0000x reference)
//
#include <hip/hip_runtime.h>

typedef __attribute__((ext_vector_type(8))) short short8;
typedef __attribute__((ext_vector_type(8))) __bf16 bf16x8;
typedef __attribute__((ext_vector_type(4))) float f32x4;
typedef __attribute__((ext_vector_type(4))) unsigned short ushort4_t;
typedef __attribute__((ext_vector_type(4))) unsigned int uint4_t;

#define NB   4096
#define NIN  4096
#define NX   4098
#define NC   128
#define NO   64
#define NA   64
#define NOUT 1024

__device__ __forceinline__ unsigned short f2bf(float f) {
  unsigned b = __builtin_bit_cast(unsigned, f);
  b += 0x7FFFu + ((b >> 16) & 1u);
  return (unsigned short)(b >> 16);
}
__device__ __forceinline__ float bf2f(unsigned short u) {
  return __builtin_bit_cast(float, (unsigned)u << 16);
}

// ---------------------------------------------------------------------------
// prep: transpose x -> xT (bf16), W -> bf16, const rows.
// ---------------------------------------------------------------------------
__global__ __launch_bounds__(256) void prep_kernel(
    const float* __restrict__ x, const float* __restrict__ W,
    unsigned short* __restrict__ xT, unsigned short* __restrict__ Wb) {
  int bid = blockIdx.x, t = threadIdx.x;
  if (bid < 4096) {
    __shared__ unsigned short tile[64][68];
    int b0 = (bid >> 6) << 6, n0 = (bid & 63) << 6;
    int r = t >> 4, c4 = (t & 15) << 2;
#pragma unroll
    for (int rr = 0; rr < 4; ++rr) {
      int row = r + rr * 16;
      float4 v = *(const float4*)(x + (size_t)(b0 + row) * NIN + n0 + c4);
      tile[row][c4 + 0] = f2bf(v.x);
      tile[row][c4 + 1] = f2bf(v.y);
      tile[row][c4 + 2] = f2bf(v.z);
      tile[row][c4 + 3] = f2bf(v.w);
    }
    __syncthreads();
#pragma unroll
    for (int rr = 0; rr < 4; ++rr) {
      int nl = r + rr * 16;
      ushort4_t o;
      o.x = tile[c4 + 0][nl];
      o.y = tile[c4 + 1][nl];
      o.z = tile[c4 + 2][nl];
      o.w = tile[c4 + 3][nl];
      *(ushort4_t*)(xT + (size_t)(n0 + nl) * NB + b0 + c4) = o;
    }
  } else if (bid < 4096 + 256) {
    size_t i0 = (size_t)(bid - 4096) * 2048 + (size_t)t * 8;
    float4 v0 = *(const float4*)(W + i0);
    float4 v1 = *(const float4*)(W + i0 + 4);
    ushort4_t a, b;
    a.x = f2bf(v0.x); a.y = f2bf(v0.y); a.z = f2bf(v0.z); a.w = f2bf(v0.w);
    b.x = f2bf(v1.x); b.y = f2bf(v1.y); b.z = f2bf(v1.z); b.w = f2bf(v1.w);
    *(ushort4_t*)(Wb + i0) = a;
    *(ushort4_t*)(Wb + i0 + 4) = b;
  } else {
    int e = (bid - 4352) * 1024 + t * 4;
    int row = e >> 12, col = e & 4095;
    unsigned short val = (row == 0) ? (unsigned short)0 : (unsigned short)0x3F80;
    ushort4_t o = {val, val, val, val};
    *(ushort4_t*)(xT + (size_t)(NIN + row) * NB + col) = o;
  }
}

__global__ __launch_bounds__(1024) void mask_kernel(
    const int* __restrict__ oidx, unsigned char* __restrict__ mask) {
  int t = threadIdx.x;
#pragma unroll
  for (int i = t; i < NC * NO; i += 1024) mask[i] = 0;
  __syncthreads();
  if (t < NOUT) {
    int idx = oidx[t];
    if (idx >= NX) mask[idx - NX] = 1;
  }
}

// ---------------------------------------------------------------------------
// cycle v6 (unchanged): gather -> reg transpose -> swizzled LDS -> MFMA ->
// LDS epilogue -> full-line stores. MODE 1: masked rows only.
// ---------------------------------------------------------------------------
template <int MODE>
__global__ __launch_bounds__(256) void cycle_kernel(
    const unsigned short* __restrict__ xT, const unsigned short* __restrict__ Wb,
    const unsigned short* __restrict__ bufPrev, unsigned short* __restrict__ bufNext,
    const int* __restrict__ axon, const unsigned char* __restrict__ mask,
    int first) {
  __shared__ __align__(16) unsigned short SM[64 * 264];
  int c = blockIdx.y;
  int t = threadIdx.x;
  int b0 = blockIdx.x << 8;
  const int* arow = axon + (c << 6);

  {
    int ao = t >> 5, bo = t & 31;
    const int* ar = arow + ao * 8;
    uint4_t rows[8];
#pragma unroll
    for (int r = 0; r < 8; ++r) {
      int idx = ar[r];
      const unsigned short* s = nullptr;
      if (idx < NX)      s = xT + (size_t)idx * NB;
      else if (!first)   s = bufPrev + (size_t)(idx - NX) * NB;
      if (s) rows[r] = *(const uint4_t*)(s + b0 + bo * 8);
      else   rows[r] = (uint4_t)(0u);
    }
    unsigned lo[4][4], hi[4][4];
#pragma unroll
    for (int p = 0; p < 4; ++p)
#pragma unroll
      for (int k = 0; k < 4; ++k) {
        unsigned wi = rows[2 * p][k], wj = rows[2 * p + 1][k];
        lo[p][k] = __builtin_amdgcn_perm(wj, wi, 0x05040100u);
        hi[p][k] = __builtin_amdgcn_perm(wj, wi, 0x07060302u);
      }
#pragma unroll
    for (int e = 0; e < 8; ++e) {
      int k = e >> 1;
      uint4_t col;
      if (e & 1) { col[0] = hi[0][k]; col[1] = hi[1][k]; col[2] = hi[2][k]; col[3] = hi[3][k]; }
      else       { col[0] = lo[0][k]; col[1] = lo[1][k]; col[2] = lo[2][k]; col[3] = lo[3][k]; }
      int b = bo * 8 + e;
      int sw = ao ^ (b & 7) ^ ((b >> 5) & 7);
      *(uint4_t*)&SM[b * 64 + (sw << 3)] = col;
    }
  }
  __syncthreads();

  int lane = t & 63, w = t >> 6;
  int ln = lane & 15, g = lane >> 4;
  const unsigned short* wrow = Wb + ((size_t)c << 12);

  f32x4 acc[4][4];
#pragma unroll
  for (int i = 0; i < 4; ++i)
#pragma unroll
    for (int j = 0; j < 4; ++j) acc[i][j] = (f32x4)(0.f);

#pragma unroll
  for (int ks = 0; ks < 2; ++ks) {
    short8 bw[4];
#pragma unroll
    for (int j = 0; j < 4; ++j)
      bw[j] = *(const short8*)(wrow + ((size_t)(j * 16 + ln) << 6) + ks * 32 + g * 8);
    short8 ag[4];
#pragma unroll
    for (int i = 0; i < 4; ++i) {
      int bl = (w << 6) + (i << 4) + ln;
      int c8 = (ks << 2) + g;
      int sw = c8 ^ (bl & 7) ^ ((bl >> 5) & 7);
      ag[i] = *(const short8*)&SM[bl * 64 + (sw << 3)];
    }
#pragma unroll
    for (int i = 0; i < 4; ++i)
#pragma unroll
      for (int j = 0; j < 4; ++j)
        acc[i][j] = __builtin_amdgcn_mfma_f32_16x16x32_bf16(
            __builtin_bit_cast(bf16x8, ag[i]), __builtin_bit_cast(bf16x8, bw[j]),
            acc[i][j], 0, 0, 0);
  }

  __syncthreads();
#pragma unroll
  for (int j = 0; j < 4; ++j) {
    int o = j * 16 + ln;
#pragma unroll
    for (int i = 0; i < 4; ++i) {
      ushort4_t pk;
#pragma unroll
      for (int r = 0; r < 4; ++r) pk[r] = f2bf(fmaxf(acc[i][j][r], 0.f));
      *(ushort4_t*)&SM[o * 264 + (w << 6) + (i << 4) + (g << 2)] = pk;
    }
  }
  __syncthreads();
#pragma unroll
  for (int it = 0; it < 16; ++it) {
    int row = it * 4 + w;
    if (MODE == 1 && mask[(c << 6) + row] == 0) continue;
    ushort4_t v = *(const ushort4_t*)&SM[row * 264 + (lane << 2)];
    *(ushort4_t*)(bufNext + ((size_t)((c << 6) + row)) * NB + b0 + (lane << 2)) = v;
  }
}

// ---------------------------------------------------------------------------
// final (unchanged)
// ---------------------------------------------------------------------------
__global__ __launch_bounds__(256) void final_kernel(
    const unsigned short* __restrict__ xT, const unsigned short* __restrict__ bufFin,
    const int* __restrict__ out_idx, float* __restrict__ out) {
  __shared__ unsigned short tile[256][66];
  int j0 = blockIdx.x << 6, b0 = blockIdx.y << 8;
  int t = threadIdx.x;
  {
    int jl = t >> 2, bq = t & 3;
    int idx = out_idx[j0 + jl];
    const unsigned short* src = (idx < NX) ? xT + (size_t)idx * NB
                                           : bufFin + (size_t)(idx - NX) * NB;
    int jcol = jl ^ (bq << 4);
#pragma unroll
    for (int k = 0; k < 8; ++k) {
      short8 v = *(const short8*)(src + b0 + bq * 64 + k * 8);
#pragma unroll
      for (int m = 0; m < 8; ++m)
        tile[bq * 64 + k * 8 + m][jcol] = (unsigned short)v[m];
    }
  }
  __syncthreads();
  {
    int j = t & 63, ws = t >> 6;
#pragma unroll
    for (int bb = 0; bb < 64; ++bb) {
      int b = bb * 4 + ws;
      int jc = j ^ ((b >> 6) << 4);
      out[(size_t)(b0 + b) * NOUT + j0 + j] = bf2f(tile[b][jc]);
    }
  }
}

// ---------------------------------------------------------------------------
// ABLATION kernels (measurement only; write nothing the pipeline reads before
// being overwritten next call). Grid (32,128) = 2x the real cycle grid so
// each dispatch exceeds the ~39us fill floor and appears in rocprof top-5.
// PH0: gather loads only.  PH1: + transpose + LDS write + barrier.
// PH2: synthetic LDS fill + ds_read + W loads + 32 MFMA (no gather/store).
// PH3: synthetic acc + LDS epilogue + full-line global stores.
// ---------------------------------------------------------------------------
template <int PH>
__global__ __launch_bounds__(256) void abl_kernel(
    const unsigned short* __restrict__ xT, const unsigned short* __restrict__ Wb,
    const unsigned short* __restrict__ bufPrev, unsigned short* __restrict__ scratch,
    const int* __restrict__ axon) {
  __shared__ __align__(16) unsigned short SM[64 * 264];
  int c = blockIdx.y;
  int t = threadIdx.x;
  int b0 = (blockIdx.x & 15) << 8;
  const int* arow = axon + (c << 6);
  int lane = t & 63, w = t >> 6, ln = lane & 15, g = lane >> 4;

  if (PH == 0 || PH == 1) {
    int ao = t >> 5, bo = t & 31;
    const int* ar = arow + ao * 8;
    uint4_t rows[8];
#pragma unroll
    for (int r = 0; r < 8; ++r) {
      int idx = ar[r];
      const unsigned short* s = (idx < NX) ? xT + (size_t)idx * NB
                                           : bufPrev + (size_t)(idx - NX) * NB;
      rows[r] = *(const uint4_t*)(s + b0 + bo * 8);
    }
    if (PH == 0) {
#pragma unroll
      for (int r = 0; r < 8; ++r)
        asm volatile("" :: "v"(rows[r][0]), "v"(rows[r][1]),
                           "v"(rows[r][2]), "v"(rows[r][3]));
      return;
    }
    unsigned lo[4][4], hi[4][4];
#pragma unroll
    for (int p = 0; p < 4; ++p)
#pragma unroll
      for (int k = 0; k < 4; ++k) {
        unsigned wi = rows[2 * p][k], wj = rows[2 * p + 1][k];
        lo[p][k] = __builtin_amdgcn_perm(wj, wi, 0x05040100u);
        hi[p][k] = __builtin_amdgcn_perm(wj, wi, 0x07060302u);
      }
#pragma unroll
    for (int e = 0; e < 8; ++e) {
      int k = e >> 1;
      uint4_t col;
      if (e & 1) { col[0] = hi[0][k]; col[1] = hi[1][k]; col[2] = hi[2][k]; col[3] = hi[3][k]; }
      else       { col[0] = lo[0][k]; col[1] = lo[1][k]; col[2] = lo[2][k]; col[3] = lo[3][k]; }
      int b = bo * 8 + e;
      int sw = ao ^ (b & 7) ^ ((b >> 5) & 7);
      *(uint4_t*)&SM[b * 64 + (sw << 3)] = col;
    }
    __syncthreads();
    unsigned v = *(unsigned*)&SM[t * 8];
    asm volatile("" :: "v"(v));
    return;
  }

  if (PH == 2) {
    // synthetic LDS content (runtime-dependent, no global gather)
#pragma unroll
    for (int k = 0; k < 8; ++k) {
      unsigned base = 0x3f803f80u ^ (unsigned)(t * 131 + k);
      uint4_t v4 = {base, base + 1, base + 2, base + 3};
      *(uint4_t*)&SM[t * 64 + k * 8] = v4;
    }
    __syncthreads();
    const unsigned short* wrow = Wb + ((size_t)c << 12);
    f32x4 acc[4][4];
#pragma unroll
    for (int i = 0; i < 4; ++i)
#pragma unroll
      for (int j = 0; j < 4; ++j) acc[i][j] = (f32x4)(0.f);
#pragma unroll
    for (int ks = 0; ks < 2; ++ks) {
      short8 bw[4];
#pragma unroll
      for (int j = 0; j < 4; ++j)
        bw[j] = *(const short8*)(wrow + ((size_t)(j * 16 + ln) << 6) + ks * 32 + g * 8);
      short8 ag[4];
#pragma unroll
      for (int i = 0; i < 4; ++i) {
        int bl = (w << 6) + (i << 4) + ln;
        int c8 = (ks << 2) + g;
        int sw = c8 ^ (bl & 7) ^ ((bl >> 5) & 7);
        ag[i] = *(const short8*)&SM[bl * 64 + (sw << 3)];
      }
#pragma unroll
      for (int i = 0; i < 4; ++i)
#pragma unroll
        for (int j = 0; j < 4; ++j)
          acc[i][j] = __builtin_amdgcn_mfma_f32_16x16x32_bf16(
              __builtin_bit_cast(bf16x8, ag[i]), __builtin_bit_cast(bf16x8, bw[j]),
              acc[i][j], 0, 0, 0);
    }
#pragma unroll
    for (int i = 0; i < 4; ++i)
#pragma unroll
      for (int j = 0; j < 4; ++j)
        asm volatile("" :: "v"(acc[i][j][0]));
    return;
  }

  if (PH == 3) {
    f32x4 acc[4][4];
#pragma unroll
    for (int i = 0; i < 4; ++i)
#pragma unroll
      for (int j = 0; j < 4; ++j) {
        float base = (float)(t + i * 17 + j * 29);
        acc[i][j] = (f32x4){base, base + 1.f, base + 2.f, base + 3.f};
      }
#pragma unroll
    for (int j = 0; j < 4; ++j) {
      int o = j * 16 + ln;
#pragma unroll
      for (int i = 0; i < 4; ++i) {
        ushort4_t pk;
#pragma unroll
        for (int r = 0; r < 4; ++r) pk[r] = f2bf(fmaxf(acc[i][j][r], 0.f));
        *(ushort4_t*)&SM[o * 264 + (w << 6) + (i << 4) + (g << 2)] = pk;
      }
    }
    __syncthreads();
#pragma unroll
    for (int it = 0; it < 16; ++it) {
      int row = it * 4 + w;
      ushort4_t v = *(const ushort4_t*)&SM[row * 264 + (lane << 2)];
      *(ushort4_t*)(scratch + ((size_t)((c << 6) + row)) * NB + b0 + (lane << 2)) = v;
    }
    return;
  }
}

// ---------------------------------------------------------------------------
extern "C" void kernel_launch(void* const* d_in, const int* in_sizes, int n_in,
                              void* d_out, int out_size, void* d_ws, size_t ws_size,
                              hipStream_t stream) {
  const float* x    = (const float*)d_in[0];
  const float* W    = (const float*)d_in[1];
  const int*   axon = (const int*)d_in[2];
  const int*   oidx = (const int*)d_in[3];
  float* out = (float*)d_out;

  const size_t XT_BYTES  = (size_t)NX * NB * 2;
  const size_t WB_BYTES  = (size_t)NC * NO * NA * 2;
  const size_t BUF_BYTES = (size_t)NC * NO * NB * 2;
  const size_t MASK_B    = 8192;
  if (ws_size < XT_BYTES + WB_BYTES + 2 * BUF_BYTES + MASK_B) return;

  char* ws = (char*)d_ws;
  unsigned short* xT   = (unsigned short*)ws;
  unsigned short* Wb   = (unsigned short*)(ws + XT_BYTES);
  unsigned short* bufA = (unsigned short*)(ws + XT_BYTES + WB_BYTES);
  unsigned short* bufB = (unsigned short*)(ws + XT_BYTES + WB_BYTES + BUF_BYTES);
  unsigned char*  mask = (unsigned char*)(ws + XT_BYTES + WB_BYTES + 2 * BUF_BYTES);

  prep_kernel<<<4360, 256, 0, stream>>>(x, W, xT, Wb);
  mask_kernel<<<1, 1024, 0, stream>>>(oidx, mask);
  dim3 cg(NB / 256, NC);
  cycle_kernel<0><<<cg, 256, 0, stream>>>(xT, Wb, bufB, bufA, axon, mask, 1);
  cycle_kernel<0><<<cg, 256, 0, stream>>>(xT, Wb, bufA, bufB, axon, mask, 0);
  cycle_kernel<0><<<cg, 256, 0, stream>>>(xT, Wb, bufB, bufA, axon, mask, 0);
  cycle_kernel<1><<<cg, 256, 0, stream>>>(xT, Wb, bufA, bufB, axon, mask, 0);
  final_kernel<<<dim3(NOUT / 64, NB / 256), 256, 0, stream>>>(xT, bufB, oidx, out);

  // ---- ablation dispatches (measurement only; bufA/bufB dead after final,
  // fully rewritten by cycles 1-2 next call before any read) ----
  dim3 ag(32, NC);
  abl_kernel<0><<<ag, 256, 0, stream>>>(xT, Wb, bufA, bufB, axon);
  abl_kernel<1><<<ag, 256, 0, stream>>>(xT, Wb, bufA, bufB, axon);
  abl_kernel<2><<<ag, 256, 0, stream>>>(xT, Wb, bufA, bufB, axon);
  abl_kernel<3><<<ag, 256, 0, stream>>>(xT, Wb, bufA, bufB, axon);
}

// Round 8
// 139.721 us; speedup vs baseline: 1.4982x; 1.4982x over previous
//
#include <hip/hip_runtime.h>

typedef __attribute__((ext_vector_type(8))) short short8;
typedef __attribute__((ext_vector_type(8))) __bf16 bf16x8;
typedef __attribute__((ext_vector_type(4))) float f32x4;
typedef __attribute__((ext_vector_type(4))) unsigned short ushort4_t;
typedef __attribute__((ext_vector_type(4))) unsigned int uint4_t;

#define NB   4096
#define NIN  4096
#define NX   4098
#define NC   128
#define NO   64
#define NA   64
#define NOUT 1024

__device__ __forceinline__ unsigned short f2bf(float f) {
  unsigned b = __builtin_bit_cast(unsigned, f);
  b += 0x7FFFu + ((b >> 16) & 1u);
  return (unsigned short)(b >> 16);
}
__device__ __forceinline__ float bf2f(unsigned short u) {
  return __builtin_bit_cast(float, (unsigned)u << 16);
}

// ---------------------------------------------------------------------------
// prep: transpose x -> xT (bf16), W -> bf16, const rows. (unchanged, ~roofline)
// ---------------------------------------------------------------------------
__global__ __launch_bounds__(256) void prep_kernel(
    const float* __restrict__ x, const float* __restrict__ W,
    unsigned short* __restrict__ xT, unsigned short* __restrict__ Wb) {
  int bid = blockIdx.x, t = threadIdx.x;
  if (bid < 4096) {
    __shared__ unsigned short tile[64][68];
    int b0 = (bid >> 6) << 6, n0 = (bid & 63) << 6;
    int r = t >> 4, c4 = (t & 15) << 2;
#pragma unroll
    for (int rr = 0; rr < 4; ++rr) {
      int row = r + rr * 16;
      float4 v = *(const float4*)(x + (size_t)(b0 + row) * NIN + n0 + c4);
      tile[row][c4 + 0] = f2bf(v.x);
      tile[row][c4 + 1] = f2bf(v.y);
      tile[row][c4 + 2] = f2bf(v.z);
      tile[row][c4 + 3] = f2bf(v.w);
    }
    __syncthreads();
#pragma unroll
    for (int rr = 0; rr < 4; ++rr) {
      int nl = r + rr * 16;
      ushort4_t o;
      o.x = tile[c4 + 0][nl];
      o.y = tile[c4 + 1][nl];
      o.z = tile[c4 + 2][nl];
      o.w = tile[c4 + 3][nl];
      *(ushort4_t*)(xT + (size_t)(n0 + nl) * NB + b0 + c4) = o;
    }
  } else if (bid < 4096 + 256) {
    size_t i0 = (size_t)(bid - 4096) * 2048 + (size_t)t * 8;
    float4 v0 = *(const float4*)(W + i0);
    float4 v1 = *(const float4*)(W + i0 + 4);
    ushort4_t a, b;
    a.x = f2bf(v0.x); a.y = f2bf(v0.y); a.z = f2bf(v0.z); a.w = f2bf(v0.w);
    b.x = f2bf(v1.x); b.y = f2bf(v1.y); b.z = f2bf(v1.z); b.w = f2bf(v1.w);
    *(ushort4_t*)(Wb + i0) = a;
    *(ushort4_t*)(Wb + i0 + 4) = b;
  } else {
    int e = (bid - 4352) * 1024 + t * 4;
    int row = e >> 12, col = e & 4095;
    unsigned short val = (row == 0) ? (unsigned short)0 : (unsigned short)0x3F80;
    ushort4_t o = {val, val, val, val};
    *(ushort4_t*)(xT + (size_t)(NIN + row) * NB + col) = o;
  }
}

// ---------------------------------------------------------------------------
// masks: gmask[r]=1 iff buffer row r is gathered by axon (read by cycles 2..4);
//        omask[r]=1 iff buffer row r is read by the final gather.
// Cycles 1-3 store only gmask rows; cycle 4 stores only omask rows.
// ---------------------------------------------------------------------------
__global__ __launch_bounds__(1024) void mask_kernel(
    const int* __restrict__ axon, const int* __restrict__ oidx,
    unsigned char* __restrict__ gmask, unsigned char* __restrict__ omask) {
  int t = threadIdx.x;
  for (int i = t; i < NC * NO; i += 1024) { gmask[i] = 0; omask[i] = 0; }
  __syncthreads();
  for (int i = t; i < NC * NA; i += 1024) {
    int idx = axon[i];
    if (idx >= NX) gmask[idx - NX] = 1;
  }
  if (t < NOUT) {
    int idx = oidx[t];
    if (idx >= NX) omask[idx - NX] = 1;
  }
}

// ---------------------------------------------------------------------------
// cycle v7: Bt=512, 512 threads (8 waves), grid (8, 128) -> all cores of one
// b-tile on one XCD (linear = y*8+x, round-robin %8 = x): buffer slice per
// XCD ~4 MB masked ~= L2, enabling cycle->cycle L2 reuse.
// Stage: wave-uniform row pointers, 1 KB contiguous per row; reg 8x8
// transpose -> swizzled LDS [b][a], addr_u16(b,a)=b*64+((a>>3)^(b&7)^
// ((b>>5)&7))*8+(a&7). MFMA per wave over 64 b. Epilogue: acc -> OS LDS
// [64][520] -> full-row stores (1 KB/instr), masked per row (both modes).
// MODE 1 additionally skips MFMA for o-groups with no masked row.
// ---------------------------------------------------------------------------
template <int MODE>
__global__ __launch_bounds__(512) void cycle_kernel(
    const unsigned short* __restrict__ xT, const unsigned short* __restrict__ Wb,
    const unsigned short* __restrict__ bufPrev, unsigned short* __restrict__ bufNext,
    const int* __restrict__ axon, const unsigned char* __restrict__ mask,
    int first) {
  // G tile: 512*64 u16 = 64 KiB.  OS tile: 64*520 u16 = 66.6 KiB. Aliased.
  __shared__ __align__(16) unsigned short SM[64 * 520];
  int c = blockIdx.y;
  int t = threadIdx.x;
  int b0 = blockIdx.x << 9;
  const int* arow = axon + (c << 6);

  int lane = t & 63, w = t >> 6;
  int ln = lane & 15, g = lane >> 4;

  // ---- stage: wave w owns row-octet ao=w (uniform ptrs); lane bo covers 16B
  {
    int ao = w, bo = lane;
    const int* ar = arow + ao * 8;
    uint4_t rows[8];
#pragma unroll
    for (int r = 0; r < 8; ++r) {
      int idx = ar[r];
      const unsigned short* s = nullptr;
      if (idx < NX)      s = xT + (size_t)idx * NB;
      else if (!first)   s = bufPrev + (size_t)(idx - NX) * NB;
      if (s) rows[r] = *(const uint4_t*)(s + b0 + bo * 8);
      else   rows[r] = (uint4_t)(0u);
    }
    unsigned lo[4][4], hi[4][4];
#pragma unroll
    for (int p = 0; p < 4; ++p)
#pragma unroll
      for (int k = 0; k < 4; ++k) {
        unsigned wi = rows[2 * p][k], wj = rows[2 * p + 1][k];
        lo[p][k] = __builtin_amdgcn_perm(wj, wi, 0x05040100u);
        hi[p][k] = __builtin_amdgcn_perm(wj, wi, 0x07060302u);
      }
#pragma unroll
    for (int e = 0; e < 8; ++e) {
      int k = e >> 1;
      uint4_t col;
      if (e & 1) { col[0] = hi[0][k]; col[1] = hi[1][k]; col[2] = hi[2][k]; col[3] = hi[3][k]; }
      else       { col[0] = lo[0][k]; col[1] = lo[1][k]; col[2] = lo[2][k]; col[3] = lo[3][k]; }
      int b = bo * 8 + e;
      int sw = ao ^ (b & 7) ^ ((b >> 5) & 7);
      *(uint4_t*)&SM[b * 64 + (sw << 3)] = col;
    }
  }
  __syncthreads();

  // ---- compute: wave w covers b-local [w*64, w*64+64) ----
  const unsigned short* wrow = Wb + ((size_t)c << 12);

  bool grp[4];
#pragma unroll
  for (int j = 0; j < 4; ++j) {
    if (MODE == 1) grp[j] = __any((int)(mask[(c << 6) + j * 16 + ln] != 0));
    else           grp[j] = true;
  }

  f32x4 acc[4][4];
#pragma unroll
  for (int i = 0; i < 4; ++i)
#pragma unroll
    for (int j = 0; j < 4; ++j) acc[i][j] = (f32x4)(0.f);

#pragma unroll
  for (int ks = 0; ks < 2; ++ks) {
    short8 ag[4];
#pragma unroll
    for (int i = 0; i < 4; ++i) {
      int bl = (w << 6) + (i << 4) + ln;
      int c8 = (ks << 2) + g;
      int sw = c8 ^ (bl & 7) ^ ((bl >> 5) & 7);
      ag[i] = *(const short8*)&SM[bl * 64 + (sw << 3)];
    }
#pragma unroll
    for (int j = 0; j < 4; ++j) {
      if (!grp[j]) continue;
      short8 bw = *(const short8*)(wrow + ((size_t)(j * 16 + ln) << 6) + ks * 32 + g * 8);
#pragma unroll
      for (int i = 0; i < 4; ++i)
        acc[i][j] = __builtin_amdgcn_mfma_f32_16x16x32_bf16(
            __builtin_bit_cast(bf16x8, ag[i]), __builtin_bit_cast(bf16x8, bw),
            acc[i][j], 0, 0, 0);
    }
  }

  // ---- epilogue: acc -> OS LDS [o=64][b=520-padded], then full-row stores
  __syncthreads();
  // frag(i,j): lane holds o = j*16+ln, b-local = w*64 + i*16 + g*4 + {0..3}
#pragma unroll
  for (int j = 0; j < 4; ++j) {
    int o = j * 16 + ln;
#pragma unroll
    for (int i = 0; i < 4; ++i) {
      ushort4_t pk;
#pragma unroll
      for (int r = 0; r < 4; ++r) pk[r] = f2bf(fmaxf(acc[i][j][r], 0.f));
      *(ushort4_t*)&SM[o * 520 + (w << 6) + (i << 4) + (g << 2)] = pk;
    }
  }
  __syncthreads();
  // wave w stores rows {it*8+w}: 64 lanes x 16 B = 1 KB contiguous per row
#pragma unroll
  for (int it = 0; it < 8; ++it) {
    int row = it * 8 + w;
    if (mask[(c << 6) + row] == 0) continue;  // wave-uniform skip
    uint4_t v = *(const uint4_t*)&SM[row * 520 + (lane << 3)];
    *(uint4_t*)(bufNext + ((size_t)((c << 6) + row)) * NB + b0 + (lane << 3)) = v;
  }
}

// ---------------------------------------------------------------------------
// final: out[b][j] = f32(pool[out_idx[j]][b]); LDS transpose for coalescing.
// ---------------------------------------------------------------------------
__global__ __launch_bounds__(256) void final_kernel(
    const unsigned short* __restrict__ xT, const unsigned short* __restrict__ bufFin,
    const int* __restrict__ out_idx, float* __restrict__ out) {
  __shared__ unsigned short tile[256][66];
  int j0 = blockIdx.x << 6, b0 = blockIdx.y << 8;
  int t = threadIdx.x;
  {
    int jl = t >> 2, bq = t & 3;
    int idx = out_idx[j0 + jl];
    const unsigned short* src = (idx < NX) ? xT + (size_t)idx * NB
                                           : bufFin + (size_t)(idx - NX) * NB;
    int jcol = jl ^ (bq << 4);
#pragma unroll
    for (int k = 0; k < 8; ++k) {
      short8 v = *(const short8*)(src + b0 + bq * 64 + k * 8);
#pragma unroll
      for (int m = 0; m < 8; ++m)
        tile[bq * 64 + k * 8 + m][jcol] = (unsigned short)v[m];
    }
  }
  __syncthreads();
  {
    int j = t & 63, ws = t >> 6;
#pragma unroll
    for (int bb = 0; bb < 64; ++bb) {
      int b = bb * 4 + ws;
      int jc = j ^ ((b >> 6) << 4);
      out[(size_t)(b0 + b) * NOUT + j0 + j] = bf2f(tile[b][jc]);
    }
  }
}

// ---------------------------------------------------------------------------
extern "C" void kernel_launch(void* const* d_in, const int* in_sizes, int n_in,
                              void* d_out, int out_size, void* d_ws, size_t ws_size,
                              hipStream_t stream) {
  const float* x    = (const float*)d_in[0];
  const float* W    = (const float*)d_in[1];
  const int*   axon = (const int*)d_in[2];
  const int*   oidx = (const int*)d_in[3];
  float* out = (float*)d_out;

  const size_t XT_BYTES  = (size_t)NX * NB * 2;        // 33,570,816
  const size_t WB_BYTES  = (size_t)NC * NO * NA * 2;   //  1,048,576
  const size_t BUF_BYTES = (size_t)NC * NO * NB * 2;   // 67,108,864
  const size_t MASK_B    = 8192;
  if (ws_size < XT_BYTES + WB_BYTES + 2 * BUF_BYTES + 2 * MASK_B) return;

  char* ws = (char*)d_ws;
  unsigned short* xT    = (unsigned short*)ws;
  unsigned short* Wb    = (unsigned short*)(ws + XT_BYTES);
  unsigned short* bufA  = (unsigned short*)(ws + XT_BYTES + WB_BYTES);
  unsigned short* bufB  = (unsigned short*)(ws + XT_BYTES + WB_BYTES + BUF_BYTES);
  unsigned char*  gmask = (unsigned char*)(ws + XT_BYTES + WB_BYTES + 2 * BUF_BYTES);
  unsigned char*  omask = gmask + MASK_B;

  prep_kernel<<<4360, 256, 0, stream>>>(x, W, xT, Wb);
  mask_kernel<<<1, 1024, 0, stream>>>(axon, oidx, gmask, omask);
  dim3 cg(NB / 512, NC);  // (8, 128): b-tile -> XCD, cores co-resident per XCD
  cycle_kernel<0><<<cg, 512, 0, stream>>>(xT, Wb, bufB, bufA, axon, gmask, 1);
  cycle_kernel<0><<<cg, 512, 0, stream>>>(xT, Wb, bufA, bufB, axon, gmask, 0);
  cycle_kernel<0><<<cg, 512, 0, stream>>>(xT, Wb, bufB, bufA, axon, gmask, 0);
  cycle_kernel<1><<<cg, 512, 0, stream>>>(xT, Wb, bufA, bufB, axon, omask, 0);
  final_kernel<<<dim3(NOUT / 64, NB / 256), 256, 0, stream>>>(xT, bufB, oidx, out);
}